// Round 15
// baseline (214.554 us; speedup 1.0000x reference)
//
#include <hip/hip_runtime.h>
#include <hip/hip_bf16.h>
#include <cstdint>

// ---------------------------------------------------------------------------
// InteractionMHA, fp32 I/O, bf16-MFMA compute.
//   scan + cvt2(Wm->bf16) + 4x gemm (Q/K) + 2x vgemm (V) + attn2 + 2x gemm_out
// Round-15: attn2 LDS 67.6KB -> 34.8KB (K staged in two 64-row halves; P and
// XT alias the same region) => 4 blocks/CU (was 2). n<=64 graphs skip the
// second K half and second XT store round via BLOCK-UNIFORM branches (phase-
// level, not r13's per-load predication). X-store keeps r14's full-line LDS
// bounce (WRITE_SIZE 90->41MB proven).
// ---------------------------------------------------------------------------

typedef short s16x8 __attribute__((ext_vector_type(8)));
typedef float f32x4 __attribute__((ext_vector_type(4)));

__device__ __forceinline__ s16x8 cvt8(const float* p) {
  float4 a0 = *(const float4*)p, a1 = *(const float4*)(p + 4);
  union { s16x8 v; __bf16 e[8]; } u;
  u.e[0] = (__bf16)a0.x; u.e[1] = (__bf16)a0.y; u.e[2] = (__bf16)a0.z; u.e[3] = (__bf16)a0.w;
  u.e[4] = (__bf16)a1.x; u.e[5] = (__bf16)a1.y; u.e[6] = (__bf16)a1.z; u.e[7] = (__bf16)a1.w;
  return u.v;
}
__device__ __forceinline__ float fast_gelu(float x) {
  float ax = fabsf(x);
  float t = 1.0f / (1.0f + 0.3275911f * (ax * 0.70710678f));
  float y = t * (0.254829592f + t * (-0.284496736f + t * (1.421413741f +
            t * (-1.453152027f + t * 1.061405429f))));
  float er = 1.0f - y * __expf(-0.5f * ax * ax);
  er = (x < 0.f) ? -er : er;
  return 0.5f * x * (1.0f + er);
}

__global__ void sentinel_kernel(float* out, float v) {
  if (threadIdx.x == 0 && blockIdx.x == 0) out[0] = v;
}

// ---------- parallel offsets scan (B <= 512), dtype self-validating --------
__global__ __launch_bounds__(512) void scan_kernel(
    const int* __restrict__ na, int* __restrict__ offs,
    int B, int total, float* out)
{
  __shared__ int s32[512];
  __shared__ int s64[512];
  const int t = threadIdx.x;
  int v32 = 0, v64 = 0;
  if (t < B) {
    v32 = na[t];
    v64 = (int)((const long long*)na)[t];
  }
  s32[t] = v32; s64[t] = v64;
  __syncthreads();
  for (int o = 1; o < 512; o <<= 1) {
    int a = (t >= o) ? s32[t - o] : 0;
    int b = (t >= o) ? s64[t - o] : 0;
    __syncthreads();
    s32[t] += a; s64[t] += b;
    __syncthreads();
  }
  int tot32 = s32[B - 1], tot64 = s64[B - 1];
  bool ok32 = (tot32 == total), ok64 = (tot64 == total);
  if (t < B) offs[t] = ok32 ? (s32[t] - v32) : ok64 ? (s64[t] - v64) : 0;
  if (t == 0) {
    offs[B] = ok32 ? tot32 : ok64 ? tot64 : 0;
    if (!ok32 && !ok64) out[0] = 31337.0f;
  }
}

// ---------- fp32 -> bf16 weight convert, both Wm in one dispatch -----------
__global__ __launch_bounds__(256) void cvt2_kernel(
    const float* __restrict__ in0, const float* __restrict__ in1,
    __bf16* __restrict__ out0, __bf16* __restrict__ out1) {
  const float* in = blockIdx.y ? in1 : in0;
  __bf16* out = blockIdx.y ? out1 : out0;
  int i = (blockIdx.x * 256 + threadIdx.x) * 4;
  float4 f = *(const float4*)(in + i);
  out[i + 0] = (__bf16)f.x; out[i + 1] = (__bf16)f.y;
  out[i + 2] = (__bf16)f.z; out[i + 3] = (__bf16)f.w;
}

// ---------- Q/K projection GEMM (proven): C = A@Bw^T + bias, bf16 ----------
__global__ __launch_bounds__(256) void gemm_kernel(
    const float* __restrict__ A, const float* __restrict__ Bw,
    const float* __restrict__ bias, __bf16* __restrict__ C, int N)
{
  __shared__ __bf16 At[128 * 32];
  __shared__ __bf16 Bt[128 * 32];
  const int t = threadIdx.x;
  const int lane = t & 63, w = t >> 6;
  const int wr = w >> 1, wc = w & 1;
  const int l15 = lane & 15, l4 = lane >> 4;
  const int by = blockIdx.x, bx = blockIdx.y;

  f32x4 acc[4][4];
  for (int m = 0; m < 4; ++m)
    for (int nn = 0; nn < 4; ++nn) acc[m][nn] = (f32x4){0.f, 0.f, 0.f, 0.f};

  for (int kk = 0; kk < 256; kk += 32) {
    for (int j = 0; j < 2; ++j) {
      int c = t + j * 256;
      int row = c >> 2, off0 = (c & 3) * 8;
      *(s16x8*)(&At[row * 32 + off0]) = cvt8(A + (size_t)(by * 128 + row) * 256 + kk + off0);
      *(s16x8*)(&Bt[row * 32 + off0]) = cvt8(Bw + (size_t)(bx * 128 + row) * 256 + kk + off0);
    }
    __syncthreads();
    s16x8 af[4], bfr[4];
    for (int m = 0; m < 4; ++m)
      af[m] = *(const s16x8*)(&At[(wr * 64 + m * 16 + l15) * 32 + l4 * 8]);
    for (int nn = 0; nn < 4; ++nn)
      bfr[nn] = *(const s16x8*)(&Bt[(wc * 64 + nn * 16 + l15) * 32 + l4 * 8]);
    for (int m = 0; m < 4; ++m)
      for (int nn = 0; nn < 4; ++nn)
        acc[m][nn] = __builtin_amdgcn_mfma_f32_16x16x32_bf16(af[m], bfr[nn], acc[m][nn], 0, 0, 0);
    __syncthreads();
  }

  for (int m = 0; m < 4; ++m) {
    int row0 = by * 128 + wr * 64 + m * 16 + l4 * 4;
    for (int nn = 0; nn < 4; ++nn) {
      int col = bx * 128 + wc * 64 + nn * 16 + l15;
      float bc = bias[col];
      for (int r = 0; r < 4; ++r) {
        int row = row0 + r;
        C[(size_t)row * N + col] = (__bf16)(acc[m][nn][r] + bc);
      }
    }
  }
}

// ---------- V projection: Vt[256][total] = Wv@rep^T + bv (row bias) --------
#define CTP 136
__global__ __launch_bounds__(256) void vgemm_kernel(
    const float* __restrict__ A, const float* __restrict__ Bw,
    const float* __restrict__ bias, __bf16* __restrict__ Vt, int total)
{
  __shared__ __bf16 At[128 * 32];
  __shared__ __bf16 Bt[128 * 32];
  __shared__ __bf16 Ct[128 * CTP];
  const int t = threadIdx.x;
  const int lane = t & 63, w = t >> 6;
  const int wr = w >> 1, wc = w & 1;
  const int l15 = lane & 15, l4 = lane >> 4;
  const int by = blockIdx.x, bx = blockIdx.y;

  f32x4 acc[4][4];
  for (int m = 0; m < 4; ++m)
    for (int nn = 0; nn < 4; ++nn) acc[m][nn] = (f32x4){0.f, 0.f, 0.f, 0.f};

  for (int kk = 0; kk < 256; kk += 32) {
    for (int j = 0; j < 2; ++j) {
      int c = t + j * 256;
      int row = c >> 2, off0 = (c & 3) * 8;
      *(s16x8*)(&At[row * 32 + off0]) = cvt8(A + (size_t)(by * 128 + row) * 256 + kk + off0);
      *(s16x8*)(&Bt[row * 32 + off0]) = cvt8(Bw + (size_t)(bx * 128 + row) * 256 + kk + off0);
    }
    __syncthreads();
    s16x8 af[4], bfr[4];
    for (int m = 0; m < 4; ++m)
      af[m] = *(const s16x8*)(&At[(wr * 64 + m * 16 + l15) * 32 + l4 * 8]);
    for (int nn = 0; nn < 4; ++nn)
      bfr[nn] = *(const s16x8*)(&Bt[(wc * 64 + nn * 16 + l15) * 32 + l4 * 8]);
    for (int m = 0; m < 4; ++m)
      for (int nn = 0; nn < 4; ++nn)
        acc[m][nn] = __builtin_amdgcn_mfma_f32_16x16x32_bf16(af[m], bfr[nn], acc[m][nn], 0, 0, 0);
    __syncthreads();
  }

  for (int m = 0; m < 4; ++m) {
    int rl0 = wr * 64 + m * 16 + l4 * 4;
    for (int nn = 0; nn < 4; ++nn) {
      int cl = wc * 64 + nn * 16 + l15;
      for (int r = 0; r < 4; ++r) {
        int rl = rl0 + r;
        Ct[rl * CTP + cl] = (__bf16)(acc[m][nn][r] + bias[by * 128 + rl]);
      }
    }
  }
  __syncthreads();

  for (int i = 0; i < 8; ++i) {
    int c = t + i * 256;
    int row = c >> 4, seg = c & 15;
    *(uint4*)(Vt + (size_t)(by * 128 + row) * total + bx * 128 + seg * 8) =
        *(const uint4*)(&Ct[row * CTP + seg * 8]);
  }
}

// ---------- merged 2-way attention, half-staged K (34.8 KB LDS) ------------
struct Attn2Args {
  const __bf16* Q[2]; const __bf16* K[2]; const __bf16* V[2];
  unsigned long long X[2];
};
#define KP 264
#define PP 136
#define XP 272
__global__ __launch_bounds__(512, 2) void attn2_kernel(
    Attn2Args args, const int* __restrict__ offs, int total)
{
  __shared__ __bf16 smem[128 * 136];              // 34816 B, K/P/XT alias
  __bf16 (*Klds)[KP] = (__bf16(*)[KP])smem;       // [64][264]
  __bf16 (*Plds)[PP] = (__bf16(*)[PP])smem;       // [128][136]
  __bf16 (*XT)[XP]   = (__bf16(*)[XP])smem;       // [64][272]

  const int br = blockIdx.y;
  const __bf16* Q  = args.Q[br];
  const __bf16* Km = args.K[br];
  const __bf16* Vt = args.V[br];
  __bf16* X = (__bf16*)args.X[br];

  const int g = blockIdx.x;
  const int off = offs[g];
  const int n = offs[g + 1] - off;
  const int t = threadIdx.x, lane = t & 63, w = t >> 6;
  const int l15 = lane & 15, l4 = lane >> 4;
  const bool qact = (w * 16) < n;
  const bool big = (n > 64);                      // block-uniform

  // ---- K half-0 stage (rows 0..63): 2048 16B chunks, 4/thread
  const int srow = t >> 5, scol = (t & 31) * 16;  // staging coords
  uint4 kst[4];
  #pragma unroll
  for (int j = 0; j < 4; ++j)
    kst[j] = *(const uint4*)((const char*)(Km + (size_t)(off + j * 16 + srow) * 256) + scol);
  // Q frags
  s16x8 qf[8];
  if (qact) {
    int qr = w * 16 + l15; if (qr >= n) qr = n - 1;
    const __bf16* qp = Q + (size_t)(off + qr) * 256 + l4 * 8;
    #pragma unroll
    for (int kk = 0; kk < 8; ++kk) qf[kk] = *(const s16x8*)(qp + kk * 32);
  }
  #pragma unroll
  for (int j = 0; j < 4; ++j)
    *(uint4*)((char*)&Klds[j * 16 + srow][0] + scol) = kst[j];
  // prefetch half-1 (retires under half-0 QK^T)
  uint4 kst1[4];
  if (big) {
    #pragma unroll
    for (int j = 0; j < 4; ++j)
      kst1[j] = *(const uint4*)((const char*)(Km + (size_t)(off + 64 + j * 16 + srow) * 256) + scol);
  }
  __syncthreads();

  // ---- QK^T half-0 (keys 0..63; out-of-range keys masked in softmax)
  f32x4 sacc[8];
  #pragma unroll
  for (int i = 0; i < 8; ++i) sacc[i] = (f32x4){0.f, 0.f, 0.f, 0.f};
  if (qact) {
    #pragma unroll
    for (int kt = 0; kt < 4; ++kt) {
      const __bf16* kp = &Klds[kt * 16 + l15][l4 * 8];
      #pragma unroll
      for (int kk = 0; kk < 8; ++kk) {
        s16x8 kf = *(const s16x8*)(kp + kk * 32);
        sacc[kt] = __builtin_amdgcn_mfma_f32_16x16x32_bf16(qf[kk], kf, sacc[kt], 0, 0, 0);
      }
    }
  }
  __syncthreads();
  if (big) {
    #pragma unroll
    for (int j = 0; j < 4; ++j)
      *(uint4*)((char*)&Klds[j * 16 + srow][0] + scol) = kst1[j];
    __syncthreads();
    if (qact) {
      #pragma unroll
      for (int kt = 0; kt < 4; ++kt) {
        const __bf16* kp = &Klds[kt * 16 + l15][l4 * 8];
        #pragma unroll
        for (int kk = 0; kk < 8; ++kk) {
          s16x8 kf = *(const s16x8*)(kp + kk * 32);
          sacc[4 + kt] = __builtin_amdgcn_mfma_f32_16x16x32_bf16(qf[kk], kf, sacc[4 + kt], 0, 0, 0);
        }
      }
    }
    __syncthreads();
  }

  // ---- softmax (regs) -> Plds (aliases dead Klds)
  if (qact) {
    #pragma unroll
    for (int r = 0; r < 4; ++r) {
      float sv[8];
      float m = -1e30f;
      #pragma unroll
      for (int kt = 0; kt < 8; ++kt) {
        int key = kt * 16 + l15;
        float v = (key < n) ? sacc[kt][r] * 0.0625f : -1e30f;
        sv[kt] = v; m = fmaxf(m, v);
      }
      for (int o = 1; o < 16; o <<= 1) m = fmaxf(m, __shfl_xor(m, o));
      float p[8], sum = 0.f;
      #pragma unroll
      for (int kt = 0; kt < 8; ++kt) { p[kt] = __expf(sv[kt] - m); sum += p[kt]; }
      for (int o = 1; o < 16; o <<= 1) sum += __shfl_xor(sum, o);
      float inv = 1.f / sum;
      int q = w * 16 + l4 * 4 + r;
      #pragma unroll
      for (int kt = 0; kt < 4; ++kt)
        Plds[q][kt * 16 + l15] = (__bf16)(p[kt] * inv);
      if (big) {
        #pragma unroll
        for (int kt = 4; kt < 8; ++kt)
          Plds[q][kt * 16 + l15] = (__bf16)(p[kt] * inv);
      }
    }
  }
  __syncthreads();

  // ---- PV: wave w computes X[all 128 q][d in w*32..+32)
  const int dbase = w * 32;
  f32x4 xacc[2][8];
  #pragma unroll
  for (int dt = 0; dt < 2; ++dt)
    #pragma unroll
    for (int qm = 0; qm < 8; ++qm) xacc[dt][qm] = (f32x4){0.f, 0.f, 0.f, 0.f};

  #pragma unroll
  for (int dt = 0; dt < 2; ++dt) {
    int d = dbase + dt * 16 + l15;
    s16x8 vf[4];
    #pragma unroll
    for (int ks = 0; ks < 4; ++ks) {
      int kc = off + ks * 32 + l4 * 8;
      if (kc > total - 8) kc = total - 8;
      vf[ks] = *(const s16x8*)(Vt + (size_t)d * total + kc);
    }
    #pragma unroll
    for (int qm = 0; qm < 8; ++qm) {
      #pragma unroll
      for (int ks = 0; ks < 4; ++ks) {
        if (ks * 32 < n) {
          s16x8 pa = *(const s16x8*)(&Plds[qm * 16 + l15][ks * 32 + l4 * 8]);
          xacc[dt][qm] = __builtin_amdgcn_mfma_f32_16x16x32_bf16(pa, vf[ks], xacc[dt][qm], 0, 0, 0);
        }
      }
    }
  }
  __syncthreads();                                // Plds dead; XT may alias

  // ---- XT round 0 (q rows 0..63) -> full-line stores
  #pragma unroll
  for (int dt = 0; dt < 2; ++dt)
    #pragma unroll
    for (int qm = 0; qm < 4; ++qm)
      #pragma unroll
      for (int r = 0; r < 4; ++r)
        XT[qm * 16 + l4 * 4 + r][dbase + dt * 16 + l15] = (__bf16)xacc[dt][qm][r];
  __syncthreads();
  #pragma unroll
  for (int i = 0; i < 4; ++i) {
    int c = t + i * 512;                          // 2048 chunks: 64 rows x 32 segs
    int row = c >> 5, seg = c & 31;
    if (row < n)
      *(uint4*)(X + (size_t)(off + row) * 256 + seg * 8) =
          *(const uint4*)(&XT[row][seg * 8]);
  }
  if (big) {
    __syncthreads();
    #pragma unroll
    for (int dt = 0; dt < 2; ++dt)
      #pragma unroll
      for (int qm = 4; qm < 8; ++qm)
        #pragma unroll
        for (int r = 0; r < 4; ++r)
          XT[(qm - 4) * 16 + l4 * 4 + r][dbase + dt * 16 + l15] = (__bf16)xacc[dt][qm][r];
    __syncthreads();
    #pragma unroll
    for (int i = 0; i < 4; ++i) {
      int c = t + i * 512;
      int row = c >> 5, seg = c & 31;
      int grow = 64 + row;
      if (grow < n)
        *(uint4*)(X + (size_t)(off + grow) * 256 + seg * 8) =
            *(const uint4*)(&XT[row][seg * 8]);
    }
  }
}

// ---------- out-proj (separate per branch, 64x128, bf16 Wm) ----------------
__global__ __launch_bounds__(256) void gemm_out(
    const __bf16* __restrict__ A, const __bf16* __restrict__ W,
    const float* __restrict__ bias, float* __restrict__ C)
{
  __shared__ __bf16 At[64 * 32];
  __shared__ __bf16 Bt[128 * 32];
  const int t = threadIdx.x;
  const int lane = t & 63, w = t >> 6;
  const int wr = w >> 1, wc = w & 1;
  const int l15 = lane & 15, l4 = lane >> 4;
  const int by = blockIdx.x, bx = blockIdx.y;

  f32x4 acc[2][4];
  for (int m = 0; m < 2; ++m)
    for (int nn = 0; nn < 4; ++nn) acc[m][nn] = (f32x4){0.f, 0.f, 0.f, 0.f};

  for (int kk = 0; kk < 256; kk += 32) {
    {
      int row = t >> 2, off0 = (t & 3) * 8;
      *(s16x8*)(&At[row * 32 + off0]) =
          *(const s16x8*)(A + (size_t)(by * 64 + row) * 256 + kk + off0);
    }
    for (int j = 0; j < 2; ++j) {
      int c = t + j * 256;
      int row = c >> 2, off0 = (c & 3) * 8;
      *(s16x8*)(&Bt[row * 32 + off0]) =
          *(const s16x8*)(W + (size_t)(bx * 128 + row) * 256 + kk + off0);
    }
    __syncthreads();
    s16x8 af[2], bfr[4];
    for (int m = 0; m < 2; ++m)
      af[m] = *(const s16x8*)(&At[(wr * 32 + m * 16 + l15) * 32 + l4 * 8]);
    for (int nn = 0; nn < 4; ++nn)
      bfr[nn] = *(const s16x8*)(&Bt[(wc * 64 + nn * 16 + l15) * 32 + l4 * 8]);
    for (int m = 0; m < 2; ++m)
      for (int nn = 0; nn < 4; ++nn)
        acc[m][nn] = __builtin_amdgcn_mfma_f32_16x16x32_bf16(af[m], bfr[nn], acc[m][nn], 0, 0, 0);
    __syncthreads();
  }

  for (int m = 0; m < 2; ++m) {
    int row0 = by * 64 + wr * 32 + m * 16 + l4 * 4;
    for (int nn = 0; nn < 4; ++nn) {
      int col = bx * 128 + wc * 64 + nn * 16 + l15;
      float bc = bias[col];
      for (int r = 0; r < 4; ++r) {
        int row = row0 + r;
        C[(size_t)row * 256 + col] = fast_gelu(acc[m][nn][r] + bc);
      }
    }
  }
}

// ---------------------------------------------------------------------------
extern "C" void kernel_launch(void* const* d_in, const int* in_sizes, int n_in,
                              void* d_out, int out_size, void* d_ws, size_t ws_size,
                              hipStream_t stream) {
  const float* rep2d = (const float*)d_in[0];
  const float* rep3d = (const float*)d_in[1];
  const int*   na    = (const int*)d_in[2];
  const float* wq23 = (const float*)d_in[3];  const float* bq23 = (const float*)d_in[4];
  const float* wk23 = (const float*)d_in[5];  const float* bk23 = (const float*)d_in[6];
  const float* wv23 = (const float*)d_in[7];  const float* bv23 = (const float*)d_in[8];
  const float* wq32 = (const float*)d_in[9];  const float* bq32 = (const float*)d_in[10];
  const float* wk32 = (const float*)d_in[11]; const float* bk32 = (const float*)d_in[12];
  const float* wv32 = (const float*)d_in[13]; const float* bv32 = (const float*)d_in[14];
  const float* wm23 = (const float*)d_in[15]; const float* bm23 = (const float*)d_in[16];
  const float* wm32 = (const float*)d_in[17]; const float* bm32 = (const float*)d_in[18];

  const int B = in_sizes[2];
  const int total = in_sizes[0] / 256;           // 40960
  float* out = (float*)d_out;

  char* ws = (char*)d_ws;
  const size_t SZ = (size_t)total * 256 * sizeof(__bf16);  // 20.97 MB
  const size_t WMB = 65536 * sizeof(__bf16);               // 128 KB
  const size_t need6 = 8192 + 2 * WMB + 6 * SZ;            // 126.1 MB (proven)
  const size_t need3 = 8192 + 2 * WMB + 3 * SZ;            // 63.2 MB (proven)
  int* offs = (int*)ws;

  dim3 blk(256);
  dim3 blkA(512);
  dim3 gP(total / 128, 2);
  dim3 gV(2, total / 128);
  dim3 gO(total / 64, 2);

  if (ws_size >= need6) {
    __bf16* WM0 = (__bf16*)(ws + 8192);
    __bf16* WM1 = (__bf16*)(ws + 8192 + WMB);
    __bf16* BQ1 = (__bf16*)(ws + 8192 + 2 * WMB);
    __bf16* BK1 = (__bf16*)(ws + 8192 + 2 * WMB + SZ);
    __bf16* BV1 = (__bf16*)(ws + 8192 + 2 * WMB + 2 * SZ);
    __bf16* BQ2 = (__bf16*)(ws + 8192 + 2 * WMB + 3 * SZ);
    __bf16* BK2 = (__bf16*)(ws + 8192 + 2 * WMB + 4 * SZ);
    __bf16* BV2 = (__bf16*)(ws + 8192 + 2 * WMB + 5 * SZ);

    scan_kernel<<<1, 512, 0, stream>>>(na, offs, B, total, out);
    cvt2_kernel<<<dim3(64, 2), blk, 0, stream>>>(wm23, wm32, WM0, WM1);
    gemm_kernel<<<gP, blk, 0, stream>>>(rep2d, wq23, bq23, BQ1, 256);
    gemm_kernel<<<gP, blk, 0, stream>>>(rep3d, wk23, bk23, BK1, 256);
    vgemm_kernel<<<gV, blk, 0, stream>>>(wv23, rep3d, bv23, BV1, total);
    gemm_kernel<<<gP, blk, 0, stream>>>(rep3d, wq32, bq32, BQ2, 256);
    gemm_kernel<<<gP, blk, 0, stream>>>(rep2d, wk32, bk32, BK2, 256);
    vgemm_kernel<<<gV, blk, 0, stream>>>(wv32, rep2d, bv32, BV2, total);

    Attn2Args aa;
    aa.Q[0] = BQ1; aa.K[0] = BK1; aa.V[0] = BV1; aa.X[0] = (unsigned long long)BQ1;
    aa.Q[1] = BQ2; aa.K[1] = BK2; aa.V[1] = BV2; aa.X[1] = (unsigned long long)BQ2;
    attn2_kernel<<<dim3(B, 2), blkA, 0, stream>>>(aa, offs, total);

    gemm_out<<<gO, blk, 0, stream>>>(BQ1, WM0, bm23, out);
    gemm_out<<<gO, blk, 0, stream>>>(BQ2, WM1, bm32, out + (size_t)total * 256);
  } else if (ws_size >= need3) {
    __bf16* WM0 = (__bf16*)(ws + 8192);
    __bf16* WM1 = (__bf16*)(ws + 8192 + WMB);
    __bf16* BQ = (__bf16*)(ws + 8192 + 2 * WMB);
    __bf16* BK = (__bf16*)(ws + 8192 + 2 * WMB + SZ);
    __bf16* BV = (__bf16*)(ws + 8192 + 2 * WMB + 2 * SZ);

    scan_kernel<<<1, 512, 0, stream>>>(na, offs, B, total, out);
    cvt2_kernel<<<dim3(64, 2), blk, 0, stream>>>(wm23, wm32, WM0, WM1);
    for (int br = 0; br < 2; ++br) {
      const float* rq = br ? rep3d : rep2d;
      const float* rk = br ? rep2d : rep3d;
      const float* wq = br ? wq32 : wq23;  const float* bq = br ? bq32 : bq23;
      const float* wk = br ? wk32 : wk23;  const float* bk = br ? bk32 : bk23;
      const float* wv = br ? wv32 : wv23;  const float* bv = br ? bv32 : bv23;
      __bf16* wm = br ? WM1 : WM0;         const float* bm = br ? bm32 : bm23;
      float* o = out + (size_t)br * total * 256;

      gemm_kernel<<<gP, blk, 0, stream>>>(rq, wq, bq, BQ, 256);
      gemm_kernel<<<gP, blk, 0, stream>>>(rk, wk, bk, BK, 256);
      vgemm_kernel<<<gV, blk, 0, stream>>>(wv, rk, bv, BV, total);
      Attn2Args aa;
      aa.Q[0] = BQ; aa.K[0] = BK; aa.V[0] = BV; aa.X[0] = (unsigned long long)BQ;
      aa.Q[1] = BQ; aa.K[1] = BK; aa.V[1] = BV; aa.X[1] = (unsigned long long)BQ;
      attn2_kernel<<<dim3(B, 1), blkA, 0, stream>>>(aa, offs, total);
      gemm_out<<<gO, blk, 0, stream>>>(BQ, wm, bm, o);
    }
  } else {
    sentinel_kernel<<<1, 64, 0, stream>>>(out, 54321.0f);
  }
}

// Round 16
// 204.921 us; speedup vs baseline: 1.0470x; 1.0470x over previous
//
#include <hip/hip_runtime.h>
#include <hip/hip_bf16.h>
#include <cstdint>

// ---------------------------------------------------------------------------
// InteractionMHA, fp32 I/O, bf16-MFMA compute.
//   scan + cvt2(Wm->bf16) + 4x gemm (Q/K) + 2x vgemm (V, TILED output) +
//   attn2 (V reads = contiguous 512B tiles) + 2x gemm_out (BK=64 full-line)
// Round-16 theory: every ws-bf16 consumer stalls at ~2.5 TB/s because its
// loads are 64B half-line segments (fp32 gemms read 128B full lines at 5.7).
// Fixes: gemm_out BK=64 staging; V stored as [ktile16][dtile16] 512B lane-
// ordered tiles so attn's V-frag load is fully contiguous.
// ---------------------------------------------------------------------------

typedef short s16x8 __attribute__((ext_vector_type(8)));
typedef float f32x4 __attribute__((ext_vector_type(4)));

__device__ __forceinline__ s16x8 cvt8(const float* p) {
  float4 a0 = *(const float4*)p, a1 = *(const float4*)(p + 4);
  union { s16x8 v; __bf16 e[8]; } u;
  u.e[0] = (__bf16)a0.x; u.e[1] = (__bf16)a0.y; u.e[2] = (__bf16)a0.z; u.e[3] = (__bf16)a0.w;
  u.e[4] = (__bf16)a1.x; u.e[5] = (__bf16)a1.y; u.e[6] = (__bf16)a1.z; u.e[7] = (__bf16)a1.w;
  return u.v;
}
__device__ __forceinline__ float fast_gelu(float x) {
  float ax = fabsf(x);
  float t = 1.0f / (1.0f + 0.3275911f * (ax * 0.70710678f));
  float y = t * (0.254829592f + t * (-0.284496736f + t * (1.421413741f +
            t * (-1.453152027f + t * 1.061405429f))));
  float er = 1.0f - y * __expf(-0.5f * ax * ax);
  er = (x < 0.f) ? -er : er;
  return 0.5f * x * (1.0f + er);
}

__global__ void sentinel_kernel(float* out, float v) {
  if (threadIdx.x == 0 && blockIdx.x == 0) out[0] = v;
}

// ---------- parallel offsets scan (B <= 512), dtype self-validating --------
__global__ __launch_bounds__(512) void scan_kernel(
    const int* __restrict__ na, int* __restrict__ offs,
    int B, int total, float* out)
{
  __shared__ int s32[512];
  __shared__ int s64[512];
  const int t = threadIdx.x;
  int v32 = 0, v64 = 0;
  if (t < B) {
    v32 = na[t];
    v64 = (int)((const long long*)na)[t];
  }
  s32[t] = v32; s64[t] = v64;
  __syncthreads();
  for (int o = 1; o < 512; o <<= 1) {
    int a = (t >= o) ? s32[t - o] : 0;
    int b = (t >= o) ? s64[t - o] : 0;
    __syncthreads();
    s32[t] += a; s64[t] += b;
    __syncthreads();
  }
  int tot32 = s32[B - 1], tot64 = s64[B - 1];
  bool ok32 = (tot32 == total), ok64 = (tot64 == total);
  if (t < B) offs[t] = ok32 ? (s32[t] - v32) : ok64 ? (s64[t] - v64) : 0;
  if (t == 0) {
    offs[B] = ok32 ? tot32 : ok64 ? tot64 : 0;
    if (!ok32 && !ok64) out[0] = 31337.0f;
  }
}

// ---------- fp32 -> bf16 weight convert, both Wm in one dispatch -----------
__global__ __launch_bounds__(256) void cvt2_kernel(
    const float* __restrict__ in0, const float* __restrict__ in1,
    __bf16* __restrict__ out0, __bf16* __restrict__ out1) {
  const float* in = blockIdx.y ? in1 : in0;
  __bf16* out = blockIdx.y ? out1 : out0;
  int i = (blockIdx.x * 256 + threadIdx.x) * 4;
  float4 f = *(const float4*)(in + i);
  out[i + 0] = (__bf16)f.x; out[i + 1] = (__bf16)f.y;
  out[i + 2] = (__bf16)f.z; out[i + 3] = (__bf16)f.w;
}

// ---------- Q/K projection GEMM (proven): C = A@Bw^T + bias, bf16 ----------
__global__ __launch_bounds__(256) void gemm_kernel(
    const float* __restrict__ A, const float* __restrict__ Bw,
    const float* __restrict__ bias, __bf16* __restrict__ C, int N)
{
  __shared__ __bf16 At[128 * 32];
  __shared__ __bf16 Bt[128 * 32];
  const int t = threadIdx.x;
  const int lane = t & 63, w = t >> 6;
  const int wr = w >> 1, wc = w & 1;
  const int l15 = lane & 15, l4 = lane >> 4;
  const int by = blockIdx.x, bx = blockIdx.y;

  f32x4 acc[4][4];
  for (int m = 0; m < 4; ++m)
    for (int nn = 0; nn < 4; ++nn) acc[m][nn] = (f32x4){0.f, 0.f, 0.f, 0.f};

  for (int kk = 0; kk < 256; kk += 32) {
    for (int j = 0; j < 2; ++j) {
      int c = t + j * 256;
      int row = c >> 2, off0 = (c & 3) * 8;
      *(s16x8*)(&At[row * 32 + off0]) = cvt8(A + (size_t)(by * 128 + row) * 256 + kk + off0);
      *(s16x8*)(&Bt[row * 32 + off0]) = cvt8(Bw + (size_t)(bx * 128 + row) * 256 + kk + off0);
    }
    __syncthreads();
    s16x8 af[4], bfr[4];
    for (int m = 0; m < 4; ++m)
      af[m] = *(const s16x8*)(&At[(wr * 64 + m * 16 + l15) * 32 + l4 * 8]);
    for (int nn = 0; nn < 4; ++nn)
      bfr[nn] = *(const s16x8*)(&Bt[(wc * 64 + nn * 16 + l15) * 32 + l4 * 8]);
    for (int m = 0; m < 4; ++m)
      for (int nn = 0; nn < 4; ++nn)
        acc[m][nn] = __builtin_amdgcn_mfma_f32_16x16x32_bf16(af[m], bfr[nn], acc[m][nn], 0, 0, 0);
    __syncthreads();
  }

  for (int m = 0; m < 4; ++m) {
    int row0 = by * 128 + wr * 64 + m * 16 + l4 * 4;
    for (int nn = 0; nn < 4; ++nn) {
      int col = bx * 128 + wc * 64 + nn * 16 + l15;
      float bc = bias[col];
      for (int r = 0; r < 4; ++r) {
        int row = row0 + r;
        C[(size_t)row * N + col] = (__bf16)(acc[m][nn][r] + bc);
      }
    }
  }
}

// ---------- V projection -> TILED layout -----------------------------------
// Vt stored as [total/16 ktiles][16 dtiles][512B]: tile (kb,db) holds
// V^T[d = db*16 + (w&15)][atom = kb*16 + (w>>4)*8 + j] at chunk w (16B each).
// attn's B-frag load becomes one 16B chunk/lane over contiguous 512B tiles.
#define CTP 136
__global__ __launch_bounds__(256) void vgemm_kernel(
    const float* __restrict__ A, const float* __restrict__ Bw,
    const float* __restrict__ bias, __bf16* __restrict__ Vt, int total)
{
  __shared__ __bf16 At[128 * 32];
  __shared__ __bf16 Bt[128 * 32];
  __shared__ __bf16 Ct[128 * CTP];
  const int t = threadIdx.x;
  const int lane = t & 63, w = t >> 6;
  const int wr = w >> 1, wc = w & 1;
  const int l15 = lane & 15, l4 = lane >> 4;
  const int by = blockIdx.x, bx = blockIdx.y;   // by: d-tile128, bx: atom-tile128

  f32x4 acc[4][4];
  for (int m = 0; m < 4; ++m)
    for (int nn = 0; nn < 4; ++nn) acc[m][nn] = (f32x4){0.f, 0.f, 0.f, 0.f};

  for (int kk = 0; kk < 256; kk += 32) {
    for (int j = 0; j < 2; ++j) {
      int c = t + j * 256;
      int row = c >> 2, off0 = (c & 3) * 8;
      *(s16x8*)(&At[row * 32 + off0]) = cvt8(A + (size_t)(by * 128 + row) * 256 + kk + off0);
      *(s16x8*)(&Bt[row * 32 + off0]) = cvt8(Bw + (size_t)(bx * 128 + row) * 256 + kk + off0);
    }
    __syncthreads();
    s16x8 af[4], bfr[4];
    for (int m = 0; m < 4; ++m)
      af[m] = *(const s16x8*)(&At[(wr * 64 + m * 16 + l15) * 32 + l4 * 8]);
    for (int nn = 0; nn < 4; ++nn)
      bfr[nn] = *(const s16x8*)(&Bt[(wc * 64 + nn * 16 + l15) * 32 + l4 * 8]);
    for (int m = 0; m < 4; ++m)
      for (int nn = 0; nn < 4; ++nn)
        acc[m][nn] = __builtin_amdgcn_mfma_f32_16x16x32_bf16(af[m], bfr[nn], acc[m][nn], 0, 0, 0);
    __syncthreads();
  }

  // +row-bias, stage 128x128 tile in LDS [d_local][atom_local]
  for (int m = 0; m < 4; ++m) {
    int rl0 = wr * 64 + m * 16 + l4 * 4;
    for (int nn = 0; nn < 4; ++nn) {
      int cl = wc * 64 + nn * 16 + l15;
      for (int r = 0; r < 4; ++r) {
        int rl = rl0 + r;
        Ct[rl * CTP + cl] = (__bf16)(acc[m][nn][r] + bias[by * 128 + rl]);
      }
    }
  }
  __syncthreads();

  // store tiled: 2048 16B chunks; 64 tiles (8 kb x 8 db) of 512B, contiguous
  for (int i = 0; i < 8; ++i) {
    int c = t + i * 256;
    int tile = c >> 5, w5 = c & 31;
    int kb_l = tile >> 3, db_l = tile & 7;
    int d_l = w5 & 15, kh = w5 >> 4;
    *(uint4*)(Vt + (((size_t)(bx * 8 + kb_l) * 16 + (by * 8 + db_l)) << 8) + w5 * 8) =
        *(const uint4*)(&Ct[(db_l * 16 + d_l) * CTP + kb_l * 16 + kh * 8]);
  }
}

// ---------- merged 2-way attention, half-staged K, tiled-V reads -----------
struct Attn2Args {
  const __bf16* Q[2]; const __bf16* K[2]; const __bf16* V[2];
  unsigned long long X[2];
};
#define KP 264
#define PP 136
#define XP 272
__global__ __launch_bounds__(512, 2) void attn2_kernel(
    Attn2Args args, const int* __restrict__ offs, int total)
{
  __shared__ __bf16 smem[128 * 136];              // 34816 B, K/P/XT alias
  __bf16 (*Klds)[KP] = (__bf16(*)[KP])smem;       // [64][264]
  __bf16 (*Plds)[PP] = (__bf16(*)[PP])smem;       // [128][136]
  __bf16 (*XT)[XP]   = (__bf16(*)[XP])smem;       // [64][272]

  const int br = blockIdx.y;
  const __bf16* Q  = args.Q[br];
  const __bf16* Km = args.K[br];
  const __bf16* Vt = args.V[br];
  __bf16* X = (__bf16*)args.X[br];

  const int g = blockIdx.x;
  const int off = offs[g];
  const int n = offs[g + 1] - off;
  const int t = threadIdx.x, lane = t & 63, w = t >> 6;
  const int l15 = lane & 15, l4 = lane >> 4;
  const bool qact = (w * 16) < n;
  const bool big = (n > 64);                      // block-uniform

  // ---- K half-0 stage (rows 0..63)
  const int srow = t >> 5, scol = (t & 31) * 16;
  uint4 kst[4];
  #pragma unroll
  for (int j = 0; j < 4; ++j)
    kst[j] = *(const uint4*)((const char*)(Km + (size_t)(off + j * 16 + srow) * 256) + scol);
  s16x8 qf[8];
  if (qact) {
    int qr = w * 16 + l15; if (qr >= n) qr = n - 1;
    const __bf16* qp = Q + (size_t)(off + qr) * 256 + l4 * 8;
    #pragma unroll
    for (int kk = 0; kk < 8; ++kk) qf[kk] = *(const s16x8*)(qp + kk * 32);
  }
  #pragma unroll
  for (int j = 0; j < 4; ++j)
    *(uint4*)((char*)&Klds[j * 16 + srow][0] + scol) = kst[j];
  uint4 kst1[4];
  if (big) {
    #pragma unroll
    for (int j = 0; j < 4; ++j)
      kst1[j] = *(const uint4*)((const char*)(Km + (size_t)(off + 64 + j * 16 + srow) * 256) + scol);
  }
  __syncthreads();

  // ---- QK^T half-0
  f32x4 sacc[8];
  #pragma unroll
  for (int i = 0; i < 8; ++i) sacc[i] = (f32x4){0.f, 0.f, 0.f, 0.f};
  if (qact) {
    #pragma unroll
    for (int kt = 0; kt < 4; ++kt) {
      const __bf16* kp = &Klds[kt * 16 + l15][l4 * 8];
      #pragma unroll
      for (int kk = 0; kk < 8; ++kk) {
        s16x8 kf = *(const s16x8*)(kp + kk * 32);
        sacc[kt] = __builtin_amdgcn_mfma_f32_16x16x32_bf16(qf[kk], kf, sacc[kt], 0, 0, 0);
      }
    }
  }
  __syncthreads();
  if (big) {
    #pragma unroll
    for (int j = 0; j < 4; ++j)
      *(uint4*)((char*)&Klds[j * 16 + srow][0] + scol) = kst1[j];
    __syncthreads();
    if (qact) {
      #pragma unroll
      for (int kt = 0; kt < 4; ++kt) {
        const __bf16* kp = &Klds[kt * 16 + l15][l4 * 8];
        #pragma unroll
        for (int kk = 0; kk < 8; ++kk) {
          s16x8 kf = *(const s16x8*)(kp + kk * 32);
          sacc[4 + kt] = __builtin_amdgcn_mfma_f32_16x16x32_bf16(qf[kk], kf, sacc[4 + kt], 0, 0, 0);
        }
      }
    }
    __syncthreads();
  }

  // ---- softmax (regs) -> Plds
  if (qact) {
    #pragma unroll
    for (int r = 0; r < 4; ++r) {
      float sv[8];
      float m = -1e30f;
      #pragma unroll
      for (int kt = 0; kt < 8; ++kt) {
        int key = kt * 16 + l15;
        float v = (key < n) ? sacc[kt][r] * 0.0625f : -1e30f;
        sv[kt] = v; m = fmaxf(m, v);
      }
      for (int o = 1; o < 16; o <<= 1) m = fmaxf(m, __shfl_xor(m, o));
      float p[8], sum = 0.f;
      #pragma unroll
      for (int kt = 0; kt < 8; ++kt) { p[kt] = __expf(sv[kt] - m); sum += p[kt]; }
      for (int o = 1; o < 16; o <<= 1) sum += __shfl_xor(sum, o);
      float inv = 1.f / sum;
      int q = w * 16 + l4 * 4 + r;
      #pragma unroll
      for (int kt = 0; kt < 4; ++kt)
        Plds[q][kt * 16 + l15] = (__bf16)(p[kt] * inv);
      if (big) {
        #pragma unroll
        for (int kt = 4; kt < 8; ++kt)
          Plds[q][kt * 16 + l15] = (__bf16)(p[kt] * inv);
      }
    }
  }
  __syncthreads();

  // ---- PV: tiled-V frag loads (contiguous 512B tiles)
  const int dbase = w * 32;
  const int ktiles = total >> 4;
  f32x4 xacc[2][8];
  #pragma unroll
  for (int dt = 0; dt < 2; ++dt)
    #pragma unroll
    for (int qm = 0; qm < 8; ++qm) xacc[dt][qm] = (f32x4){0.f, 0.f, 0.f, 0.f};

  #pragma unroll
  for (int dt = 0; dt < 2; ++dt) {
    int db = w * 2 + dt;
    s16x8 vf[4];
    #pragma unroll
    for (int ks = 0; ks < 4; ++ks) {
      int kb = (off >> 4) + ks * 2 + (l4 >> 1);
      if (kb >= ktiles) kb = ktiles - 1;        // P=0 there; finite data
      vf[ks] = *(const s16x8*)(Vt + (((size_t)kb * 16 + db) << 8)
                               + (l15 + ((l4 & 1) << 4)) * 8);
    }
    #pragma unroll
    for (int qm = 0; qm < 8; ++qm) {
      #pragma unroll
      for (int ks = 0; ks < 4; ++ks) {
        if (ks * 32 < n) {
          s16x8 pa = *(const s16x8*)(&Plds[qm * 16 + l15][ks * 32 + l4 * 8]);
          xacc[dt][qm] = __builtin_amdgcn_mfma_f32_16x16x32_bf16(pa, vf[ks], xacc[dt][qm], 0, 0, 0);
        }
      }
    }
  }
  __syncthreads();                                // Plds dead; XT aliases

  // ---- XT round 0 (q rows 0..63) -> full-line stores
  #pragma unroll
  for (int dt = 0; dt < 2; ++dt)
    #pragma unroll
    for (int qm = 0; qm < 4; ++qm)
      #pragma unroll
      for (int r = 0; r < 4; ++r)
        XT[qm * 16 + l4 * 4 + r][dbase + dt * 16 + l15] = (__bf16)xacc[dt][qm][r];
  __syncthreads();
  #pragma unroll
  for (int i = 0; i < 4; ++i) {
    int c = t + i * 512;
    int row = c >> 5, seg = c & 31;
    if (row < n)
      *(uint4*)(X + (size_t)(off + row) * 256 + seg * 8) =
          *(const uint4*)(&XT[row][seg * 8]);
  }
  if (big) {
    __syncthreads();
    #pragma unroll
    for (int dt = 0; dt < 2; ++dt)
      #pragma unroll
      for (int qm = 4; qm < 8; ++qm)
        #pragma unroll
        for (int r = 0; r < 4; ++r)
          XT[(qm - 4) * 16 + l4 * 4 + r][dbase + dt * 16 + l15] = (__bf16)xacc[dt][qm][r];
    __syncthreads();
    #pragma unroll
    for (int i = 0; i < 4; ++i) {
      int c = t + i * 512;
      int row = c >> 5, seg = c & 31;
      int grow = 64 + row;
      if (grow < n)
        *(uint4*)(X + (size_t)(off + grow) * 256 + seg * 8) =
            *(const uint4*)(&XT[row][seg * 8]);
    }
  }
}

// ---------- out-proj (per branch, 64x128 tiles, BK=64 full-line staging) ---
#define OP 88
__global__ __launch_bounds__(256) void gemm_out(
    const __bf16* __restrict__ A, const __bf16* __restrict__ W,
    const float* __restrict__ bias, float* __restrict__ C)
{
  __shared__ __bf16 At[64 * OP];    // 11.3 KB, pitch 88 (~2-way banks)
  __shared__ __bf16 Bt[128 * OP];   // 22.5 KB
  const int t = threadIdx.x;
  const int lane = t & 63, w = t >> 6;
  const int wr = w >> 1, wc = w & 1;
  const int l15 = lane & 15, l4 = lane >> 4;
  const int by = blockIdx.x, bx = blockIdx.y;

  f32x4 acc[2][4];
  for (int m = 0; m < 2; ++m)
    for (int nn = 0; nn < 4; ++nn) acc[m][nn] = (f32x4){0.f, 0.f, 0.f, 0.f};

  for (int kk = 0; kk < 256; kk += 64) {
    // A: 64 rows x 64 elems (128B/row, full lines): 512 chunks, 2/thread
    #pragma unroll
    for (int j = 0; j < 2; ++j) {
      int c = t + j * 256;
      int row = c >> 3, off0 = (c & 7) * 8;
      *(s16x8*)(&At[row * OP + off0]) =
          *(const s16x8*)(A + (size_t)(by * 64 + row) * 256 + kk + off0);
    }
    // B: 128 rows x 64 elems: 1024 chunks, 4/thread
    #pragma unroll
    for (int j = 0; j < 4; ++j) {
      int c = t + j * 256;
      int row = c >> 3, off0 = (c & 7) * 8;
      *(s16x8*)(&Bt[row * OP + off0]) =
          *(const s16x8*)(W + (size_t)(bx * 128 + row) * 256 + kk + off0);
    }
    __syncthreads();
    #pragma unroll
    for (int k2 = 0; k2 < 2; ++k2) {
      s16x8 af[2], bfr[4];
      #pragma unroll
      for (int m = 0; m < 2; ++m)
        af[m] = *(const s16x8*)(&At[(wr * 32 + m * 16 + l15) * OP + k2 * 32 + l4 * 8]);
      #pragma unroll
      for (int nn = 0; nn < 4; ++nn)
        bfr[nn] = *(const s16x8*)(&Bt[(wc * 64 + nn * 16 + l15) * OP + k2 * 32 + l4 * 8]);
      #pragma unroll
      for (int m = 0; m < 2; ++m)
        #pragma unroll
        for (int nn = 0; nn < 4; ++nn)
          acc[m][nn] = __builtin_amdgcn_mfma_f32_16x16x32_bf16(af[m], bfr[nn], acc[m][nn], 0, 0, 0);
    }
    __syncthreads();
  }

  for (int m = 0; m < 2; ++m) {
    int row0 = by * 64 + wr * 32 + m * 16 + l4 * 4;
    for (int nn = 0; nn < 4; ++nn) {
      int col = bx * 128 + wc * 64 + nn * 16 + l15;
      float bc = bias[col];
      for (int r = 0; r < 4; ++r) {
        int row = row0 + r;
        C[(size_t)row * 256 + col] = fast_gelu(acc[m][nn][r] + bc);
      }
    }
  }
}

// ---------------------------------------------------------------------------
extern "C" void kernel_launch(void* const* d_in, const int* in_sizes, int n_in,
                              void* d_out, int out_size, void* d_ws, size_t ws_size,
                              hipStream_t stream) {
  const float* rep2d = (const float*)d_in[0];
  const float* rep3d = (const float*)d_in[1];
  const int*   na    = (const int*)d_in[2];
  const float* wq23 = (const float*)d_in[3];  const float* bq23 = (const float*)d_in[4];
  const float* wk23 = (const float*)d_in[5];  const float* bk23 = (const float*)d_in[6];
  const float* wv23 = (const float*)d_in[7];  const float* bv23 = (const float*)d_in[8];
  const float* wq32 = (const float*)d_in[9];  const float* bq32 = (const float*)d_in[10];
  const float* wk32 = (const float*)d_in[11]; const float* bk32 = (const float*)d_in[12];
  const float* wv32 = (const float*)d_in[13]; const float* bv32 = (const float*)d_in[14];
  const float* wm23 = (const float*)d_in[15]; const float* bm23 = (const float*)d_in[16];
  const float* wm32 = (const float*)d_in[17]; const float* bm32 = (const float*)d_in[18];

  const int B = in_sizes[2];
  const int total = in_sizes[0] / 256;           // 40960
  float* out = (float*)d_out;

  char* ws = (char*)d_ws;
  const size_t SZ = (size_t)total * 256 * sizeof(__bf16);  // 20.97 MB
  const size_t WMB = 65536 * sizeof(__bf16);               // 128 KB
  const size_t need6 = 8192 + 2 * WMB + 6 * SZ;            // 126.1 MB (proven)
  const size_t need3 = 8192 + 2 * WMB + 3 * SZ;            // 63.2 MB (proven)
  int* offs = (int*)ws;

  dim3 blk(256);
  dim3 blkA(512);
  dim3 gP(total / 128, 2);
  dim3 gV(2, total / 128);
  dim3 gO(total / 64, 2);

  if (ws_size >= need6) {
    __bf16* WM0 = (__bf16*)(ws + 8192);
    __bf16* WM1 = (__bf16*)(ws + 8192 + WMB);
    __bf16* BQ1 = (__bf16*)(ws + 8192 + 2 * WMB);
    __bf16* BK1 = (__bf16*)(ws + 8192 + 2 * WMB + SZ);
    __bf16* BV1 = (__bf16*)(ws + 8192 + 2 * WMB + 2 * SZ);
    __bf16* BQ2 = (__bf16*)(ws + 8192 + 2 * WMB + 3 * SZ);
    __bf16* BK2 = (__bf16*)(ws + 8192 + 2 * WMB + 4 * SZ);
    __bf16* BV2 = (__bf16*)(ws + 8192 + 2 * WMB + 5 * SZ);

    scan_kernel<<<1, 512, 0, stream>>>(na, offs, B, total, out);
    cvt2_kernel<<<dim3(64, 2), blk, 0, stream>>>(wm23, wm32, WM0, WM1);
    gemm_kernel<<<gP, blk, 0, stream>>>(rep2d, wq23, bq23, BQ1, 256);
    gemm_kernel<<<gP, blk, 0, stream>>>(rep3d, wk23, bk23, BK1, 256);
    vgemm_kernel<<<gV, blk, 0, stream>>>(wv23, rep3d, bv23, BV1, total);
    gemm_kernel<<<gP, blk, 0, stream>>>(rep3d, wq32, bq32, BQ2, 256);
    gemm_kernel<<<gP, blk, 0, stream>>>(rep2d, wk32, bk32, BK2, 256);
    vgemm_kernel<<<gV, blk, 0, stream>>>(wv32, rep2d, bv32, BV2, total);

    Attn2Args aa;
    aa.Q[0] = BQ1; aa.K[0] = BK1; aa.V[0] = BV1; aa.X[0] = (unsigned long long)BQ1;
    aa.Q[1] = BQ2; aa.K[1] = BK2; aa.V[1] = BV2; aa.X[1] = (unsigned long long)BQ2;
    attn2_kernel<<<dim3(B, 2), blkA, 0, stream>>>(aa, offs, total);

    gemm_out<<<gO, blk, 0, stream>>>(BQ1, WM0, bm23, out);
    gemm_out<<<gO, blk, 0, stream>>>(BQ2, WM1, bm32, out + (size_t)total * 256);
  } else if (ws_size >= need3) {
    __bf16* WM0 = (__bf16*)(ws + 8192);
    __bf16* WM1 = (__bf16*)(ws + 8192 + WMB);
    __bf16* BQ = (__bf16*)(ws + 8192 + 2 * WMB);
    __bf16* BK = (__bf16*)(ws + 8192 + 2 * WMB + SZ);
    __bf16* BV = (__bf16*)(ws + 8192 + 2 * WMB + 2 * SZ);

    scan_kernel<<<1, 512, 0, stream>>>(na, offs, B, total, out);
    cvt2_kernel<<<dim3(64, 2), blk, 0, stream>>>(wm23, wm32, WM0, WM1);
    for (int br = 0; br < 2; ++br) {
      const float* rq = br ? rep3d : rep2d;
      const float* rk = br ? rep2d : rep3d;
      const float* wq = br ? wq32 : wq23;  const float* bq = br ? bq32 : bq23;
      const float* wk = br ? wk32 : wk23;  const float* bk = br ? bk32 : bk23;
      const float* wv = br ? wv32 : wv23;  const float* bv = br ? bv32 : bv23;
      __bf16* wm = br ? WM1 : WM0;         const float* bm = br ? bm32 : bm23;
      float* o = out + (size_t)br * total * 256;

      gemm_kernel<<<gP, blk, 0, stream>>>(rq, wq, bq, BQ, 256);
      gemm_kernel<<<gP, blk, 0, stream>>>(rk, wk, bk, BK, 256);
      vgemm_kernel<<<gV, blk, 0, stream>>>(wv, rk, bv, BV, total);
      Attn2Args aa;
      aa.Q[0] = BQ; aa.K[0] = BK; aa.V[0] = BV; aa.X[0] = (unsigned long long)BQ;
      aa.Q[1] = BQ; aa.K[1] = BK; aa.V[1] = BV; aa.X[1] = (unsigned long long)BQ;
      attn2_kernel<<<dim3(B, 1), blkA, 0, stream>>>(aa, offs, total);
      gemm_out<<<gO, blk, 0, stream>>>(BQ, wm, bm, o);
    }
  } else {
    sentinel_kernel<<<1, 64, 0, stream>>>(out, 54321.0f);
  }
}